// Round 7
// baseline (1280.531 us; speedup 1.0000x reference)
//
#include <hip/hip_runtime.h>

#define DI __device__ __forceinline__

typedef __attribute__((ext_vector_type(8))) short short8;
typedef __attribute__((ext_vector_type(4))) float f32x4;

constexpr int THREADS = 1024;          // 16 waves -> 4 waves/SIMD (VGPR cap 128)
constexpr int ROWS    = 32;            // batch rows per block
constexpr int NBLK    = 8192 / ROWS;   // 256 blocks = 256 CUs
constexpr int PW      = 264;           // K=128 bf16 row pitch; 66 dwords == 2-bank shift -> conflict-free b128
constexpr int PITCH2  = 528;           // K=256 rows (a1 / W32)

// ---- LDS layout (bytes), total 157184 <= 163840 ----
constexpr int O_WIH   = 0;        // 101376 = 384*264: enc/dec_wih B-matrix (persistent); decoder staging + W32
constexpr int O_XALL  = 101376;   // 16896 = 64*264: x_all (2 steps x 32 rows); init: conv-w build; decoder: a1
constexpr int O_H     = 118272;   // 33792 = 2*16896: h double buffer; init: whh staging rounds
constexpr int HBUF    = 16896;
constexpr int O_PATCH = 152064;   // 5120 = 64 rows x 80B (2 steps x 32 rows)
constexpr int LDS_TOTAL = 157184;
// decoder aliases
constexpr int O_A1D   = O_XALL;   // 16896 = 32 x 528
constexpr int O_W32   = 0;        // 8448 = 16 x 528 fused (fc3@fc2) bf16
constexpr int O_B32   = 8448;     // 24: fused bias f32(6)
constexpr int O_CW    = O_XALL;   // init: conv weights 128 x 80

// HW packed f32->bf16 (RNE), 1 instr; no builtin on gfx950 -> inline asm.
DI unsigned cvtpk2(float lo, float hi){
  unsigned r;
  asm("v_cvt_pk_bf16_f32 %0, %1, %2" : "=v"(r) : "v"(lo), "v"(hi));
  return r;
}
DI unsigned short f2bf(float f){ return (unsigned short)cvtpk2(f, f); }
// rcp-based activations (v_rcp_f32, ~1 ulp); saturation correct (rcp(inf)=0).
DI float sigm(float x){ return __builtin_amdgcn_rcpf(1.f + __expf(-x)); }
DI float tanh_(float x){ return 2.f * __builtin_amdgcn_rcpf(1.f + __expf(-2.f * x)) - 1.f; }
DI f32x4 mfma16(short8 a, short8 b, f32x4 c){
  return __builtin_amdgcn_mfma_f32_16x16x32_bf16(a, b, c, 0, 0, 0);
}

// stage (nrows x 128) f32 -> bf16 LDS rows at pitch PW
DI void stage_k128p(char* dst, const float* __restrict__ src, int nrows, int tid){
  const int total = nrows * 32;
  for (int i = tid; i < total; i += THREADS){
    float4 v = ((const float4*)src)[i];
    int e = i << 2;
    int n = e >> 7, k = e & 127;
    *(uint2*)(dst + n * PW + k * 2) = make_uint2(cvtpk2(v.x, v.y), cvtpk2(v.z, v.w));
  }
}

__global__ void __launch_bounds__(THREADS, 1)
gru_fused(const float* __restrict__ past,
          const float* __restrict__ conv_w, const float* __restrict__ conv_b,
          const float* __restrict__ bn_gamma, const float* __restrict__ bn_beta,
          const float* __restrict__ bn_mean, const float* __restrict__ bn_var,
          const float* __restrict__ enc_wih, const float* __restrict__ enc_whh,
          const float* __restrict__ enc_bih, const float* __restrict__ enc_bhh,
          const float* __restrict__ dec_wih, const float* __restrict__ dec_whh,
          const float* __restrict__ dec_bih, const float* __restrict__ dec_bhh,
          const float* __restrict__ fc1_w, const float* __restrict__ fc1_b,
          const float* __restrict__ fc2_w, const float* __restrict__ fc2_b,
          const float* __restrict__ fc3_w, const float* __restrict__ fc3_b,
          float* __restrict__ out)
{
  extern __shared__ char smem[];
  const int tid  = threadIdx.x;
  const int lane = tid & 63, w = tid >> 6;        // 16 waves
  const int l15  = lane & 15, quad = lane >> 4;
  const int jg   = w >> 1, mt = w & 1;            // colgroup 0..7, row-half 0..1
  const int b0   = blockIdx.x * ROWS;
  const int col  = jg * 16 + l15;                 // gate hidden-col (0..127)

  // ---- encoder-phase bias registers only (decoder biases loaded later) ----
  const float br_e  = enc_bih[col]       + enc_bhh[col];
  const float bz_e  = enc_bih[128 + col] + enc_bhh[128 + col];
  const float bin_e = enc_bih[256 + col];
  const float bhn_e = enc_bhh[256 + col];
  const float cb_t  = conv_b[col];
  const float s_bn  = bn_gamma[0] * rsqrtf(bn_var[0] + 1e-5f);
  const float o_bn  = bn_beta[0] - bn_mean[0] * s_bn;

  // ---- stage enc_wih -> persistent LDS B-matrix (read per gi_unit) ----
  stage_k128p(smem + O_WIH, enc_wih, 384, tid);
  // ---- enc_whh B-frags -> registers (staged per gate through the h region) ----
  short8 wh[3][4];
  #pragma unroll
  for (int g = 0; g < 3; ++g){
    stage_k128p(smem + O_H, enc_whh + g*16384, 128, tid);
    __syncthreads();
    #pragma unroll
    for (int kt = 0; kt < 4; ++kt)
      wh[g][kt] = *(const short8*)(smem + O_H + col*PW + kt*64 + quad*16);
    __syncthreads();
  }
  // ---- conv weights cwT[oc][k=c*3+kk], 80B rows, K padded 18->32 (zeros annihilate A garbage) ----
  for (int i = tid; i < 2560; i += THREADS) ((unsigned*)(smem + O_CW))[i] = 0u;
  __syncthreads();
  for (int i = tid; i < 2304; i += THREADS){
    int oc = i / 18, kk = i - oc * 18;
    *(unsigned short*)(smem + O_CW + oc*80 + kk*2) = f2bf(conv_w[i]);
  }
  __syncthreads();
  const short8 cwf = *(const short8*)(smem + O_CW + col*80 + quad*16);
  __syncthreads();
  // ---- zero h double buffer ----
  for (int i = tid; i < 2*HBUF/4; i += THREADS) ((unsigned*)(smem + O_H))[i] = 0u;

  // patch constants: 576 entries (32 rows x 18); tid<576 handles one
  const int m0 = tid / 18, r0 = tid - m0*18, c0 = r0 / 3, k0 = r0 - c0*3;
  float pf0 = 0.f, pf1 = 0.f;     // prefetched patch values (chunk in flight)
  // load chunk (t0): patch(tc,m,r18) = past[m][c][t0+tc+k-1]
  auto patch_load = [&](int t0){
    if (tid < 576){
      int ts = t0 + k0 - 1;
      const float* pp = past + (size_t)(b0 + m0)*768 + c0*128;
      pf0 = (ts >= 0 && ts < 128) ? pp[ts] : 0.f;
      pf1 = (ts + 1 < 128)        ? pp[ts + 1] : 0.f;    // ts+1 >= 0 always
    }
  };
  auto patch_store = [&](){
    if (tid < 576){
      char* pb = smem + O_PATCH + m0*80 + r0*2;
      *(unsigned short*)(pb)        = f2bf(pf0);          // tc = 0
      *(unsigned short*)(pb + 2560) = f2bf(pf1);          // tc = 1
    }
  };

  // ---- per-thread state ----
  f32x4 gi_f[2][3];                       // f32 gi for 2 steps: [tc][gate] (24 regs)
  float hreg[4] = {0.f, 0.f, 0.f, 0.f};

  // conv: 64 rows x 128 cols; wave (mt,jg) does rowtiles {mt, mt+2}, coltile jg
  auto conv_block = [&](){
    #pragma unroll
    for (int rr = 0; rr < 2; ++rr){
      const int rt = mt + rr*2;
      short8 pa = *(const short8*)(smem + O_PATCH + (rt*16 + l15)*80 + quad*16);
      f32x4 cc = (f32x4){0.f,0.f,0.f,0.f};
      cc = mfma16(pa, cwf, cc);
      #pragma unroll
      for (int r = 0; r < 4; ++r){
        float vx = s_bn * fmaxf(cc[r] + cb_t, 0.f) + o_bn;
        *(unsigned short*)(smem + O_XALL + (rt*16 + quad*4 + r)*PW + col*2) = f2bf(vx);
      }
    }
  };
  // gi for (tc, wave's mt): A from x_all, B from wih LDS
  auto gi_unit = [&](int tc){
    short8 a[4];
    #pragma unroll
    for (int kt = 0; kt < 4; ++kt)
      a[kt] = *(const short8*)(smem + O_XALL + (tc*32 + mt*16 + l15)*PW + kt*64 + quad*16);
    f32x4 g0 = (f32x4){0.f,0.f,0.f,0.f}, g1 = g0, g2 = g0;
    #pragma unroll
    for (int kt = 0; kt < 4; ++kt){
      short8 b0f = *(const short8*)(smem + O_WIH + (       col)*PW + kt*64 + quad*16);
      short8 b1f = *(const short8*)(smem + O_WIH + (128 + col)*PW + kt*64 + quad*16);
      short8 b2f = *(const short8*)(smem + O_WIH + (256 + col)*PW + kt*64 + quad*16);
      g0 = mfma16(a[kt], b0f, g0);
      g1 = mfma16(a[kt], b1f, g1);
      g2 = mfma16(a[kt], b2f, g2);
    }
    gi_f[tc][0] = g0; gi_f[tc][1] = g1; gi_f[tc][2] = g2;
  };
  // one recurrent step (12 MFMA, 4 gate elements); no barrier inside
  auto step_body = [&](int t, int tc){
    const char* hr = smem + O_H + (t & 1) * HBUF;
    char*       hw = smem + O_H + ((t + 1) & 1) * HBUF;
    f32x4 accr = gi_f[tc][0], accz = gi_f[tc][1], gin = gi_f[tc][2];
    f32x4 accn2 = (f32x4){0.f,0.f,0.f,0.f};
    short8 ha[4];
    #pragma unroll
    for (int kt = 0; kt < 4; ++kt)
      ha[kt] = *(const short8*)(hr + (mt*16 + l15)*PW + kt*64 + quad*16);
    #pragma unroll
    for (int kt = 0; kt < 4; ++kt){
      accr  = mfma16(ha[kt], wh[0][kt], accr);
      accz  = mfma16(ha[kt], wh[1][kt], accz);
      accn2 = mfma16(ha[kt], wh[2][kt], accn2);
    }
    #pragma unroll
    for (int r = 0; r < 4; ++r){
      float rg = sigm(accr[r] + br_e);
      float zg = sigm(accz[r] + bz_e);
      float ng = tanh_(gin[r] + bin_e + rg*(accn2[r] + bhn_e));
      hreg[r] = ng + zg*(hreg[r] - ng);
    }
    #pragma unroll
    for (int r = 0; r < 4; ++r)
      *(unsigned short*)(hw + (mt*16 + quad*4 + r)*PW + col*2) = f2bf(hreg[r]);
  };

  // ================= encoder: 64 chunks of 2 steps, software-pipelined =================
  __syncthreads();                 // wih/cw/h-zero visible
  patch_load(0); patch_store();    // patch <- chunk 0
  __syncthreads();
  conv_block();                    // x_all <- chunk 0
  patch_load(2);                   // prefetch chunk 1
  __syncthreads();
  gi_unit(0); gi_unit(1);          // gi(chunk 0)
  patch_store();                   // patch <- chunk 1
  __syncthreads();

  // Invariant at top of chunk c: gi_f = gi(c); patch = chunk c+1; pf = (c+2 loaded at step0)
  for (int c = 0; c < 64; ++c){
    const int t0 = c * 2;
    const bool prod = (c < 63);
    step_body(t0, 0);
    if (prod){ conv_block(); if (c < 62) patch_load(t0 + 4); }
    __syncthreads();
    step_body(t0 + 1, 1);
    if (prod){ gi_unit(0); gi_unit(1); if (c < 62) patch_store(); }
    __syncthreads();
  }
  // h_enc lives in h buffer 0 (t=128 -> buf 0)

  // ================= decoder init =================
  stage_k128p(smem + O_WIH, dec_wih, 384, tid);
  __syncthreads();
  f32x4 gi0r = (f32x4){0.f,0.f,0.f,0.f}, gi0z = gi0r, gi0n = gi0r;
  {
    short8 hea[4];
    #pragma unroll
    for (int kt = 0; kt < 4; ++kt)
      hea[kt] = *(const short8*)(smem + O_H + (mt*16 + l15)*PW + kt*64 + quad*16);
    #pragma unroll
    for (int kt = 0; kt < 4; ++kt){
      short8 b0f = *(const short8*)(smem + O_WIH + (       col)*PW + kt*64 + quad*16);
      short8 b1f = *(const short8*)(smem + O_WIH + (128 + col)*PW + kt*64 + quad*16);
      short8 b2f = *(const short8*)(smem + O_WIH + (256 + col)*PW + kt*64 + quad*16);
      gi0r = mfma16(hea[kt], b0f, gi0r);
      gi0z = mfma16(hea[kt], b1f, gi0z);
      gi0n = mfma16(hea[kt], b2f, gi0n);
    }
  }
  __syncthreads();
  stage_k128p(smem + O_WIH, dec_whh, 384, tid);
  __syncthreads();
  #pragma unroll
  for (int g = 0; g < 3; ++g)
    #pragma unroll
    for (int kt = 0; kt < 4; ++kt)
      wh[g][kt] = *(const short8*)(smem + O_WIH + (g*128 + col)*PW + kt*64 + quad*16);
  __syncthreads();
  stage_k128p(smem + O_WIH, fc1_w, 256, tid);
  __syncthreads();
  short8 f1f[4];
  #pragma unroll
  for (int kt = 0; kt < 4; ++kt)
    f1f[kt] = *(const short8*)(smem + O_WIH + (w*16 + l15)*PW + kt*64 + quad*16);
  __syncthreads();
  // fused W32 = fc3_w @ fc2_w (6x256) bf16 B-layout (16 rows x 528) + fused bias
  for (int i = tid; i < 2112; i += THREADS) ((unsigned*)(smem + O_W32))[i] = 0u;
  __syncthreads();
  if (tid < 512){
    const int kk = tid & 255, wn = (tid >> 8) * 3;
    float o0 = 0.f, o1 = 0.f, o2 = 0.f;
    for (int jj = 0; jj < 64; ++jj){
      float cv = fc2_w[jj*256 + kk];
      o0 += fc3_w[(wn+0)*64 + jj] * cv;
      o1 += fc3_w[(wn+1)*64 + jj] * cv;
      o2 += fc3_w[(wn+2)*64 + jj] * cv;
    }
    *(unsigned short*)(smem + O_W32 + (wn+0)*PITCH2 + kk*2) = f2bf(o0);
    *(unsigned short*)(smem + O_W32 + (wn+1)*PITCH2 + kk*2) = f2bf(o1);
    *(unsigned short*)(smem + O_W32 + (wn+2)*PITCH2 + kk*2) = f2bf(o2);
  }
  if (tid < 6){
    float ob = fc3_b[tid];
    for (int jj = 0; jj < 64; ++jj) ob += fc3_w[tid*64 + jj] * fc2_b[jj];
    ((float*)(smem + O_B32))[tid] = ob;
  }
  // decoder biases (kept out of encoder live range)
  const float br_d  = dec_bih[col]       + dec_bhh[col];
  const float bz_d  = dec_bih[128 + col] + dec_bhh[128 + col];
  const float bin_d = dec_bih[256 + col];
  const float bhn_d = dec_bhh[256 + col];
  const float fb1   = fc1_b[w*16 + l15];
  // zero decoder h0 (buffer 1), reset hreg
  for (int i = tid; i < HBUF/4; i += THREADS) ((unsigned*)(smem + O_H + HBUF))[i] = 0u;
  #pragma unroll
  for (int i = 0; i < 4; ++i) hreg[i] = 0.f;
  __syncthreads();
  float pres[4] = {0.f, 0.f, 0.f, 0.f};
  float b32v = 0.f;
  if (w < 2 && l15 < 6){
    b32v = ((const float*)(smem + O_B32))[l15];
    #pragma unroll
    for (int r = 0; r < 4; ++r)
      pres[r] = past[(size_t)(b0 + w*16 + quad*4 + r)*768 + l15*128 + 127];
  }

  // ================= decoder: 30 steps, 2 barriers each =================
  for (int s = 0; s < 30; ++s){
    const char* hr = smem + O_H + (1 - (s & 1)) * HBUF;
    char*       hw = smem + O_H + (s & 1) * HBUF;
    f32x4 accr, accz, gin;
    if (s == 0){ accr = gi0r; accz = gi0z; gin = gi0n; }
    else       { accr = (f32x4){0.f,0.f,0.f,0.f}; accz = accr; gin = accr; }
    f32x4 accn2 = (f32x4){0.f,0.f,0.f,0.f};
    {
      short8 ha[4];
      #pragma unroll
      for (int kt = 0; kt < 4; ++kt)
        ha[kt] = *(const short8*)(hr + (mt*16 + l15)*PW + kt*64 + quad*16);
      #pragma unroll
      for (int kt = 0; kt < 4; ++kt){
        accr  = mfma16(ha[kt], wh[0][kt], accr);
        accz  = mfma16(ha[kt], wh[1][kt], accz);
        accn2 = mfma16(ha[kt], wh[2][kt], accn2);
      }
    }
    #pragma unroll
    for (int r = 0; r < 4; ++r){
      float rg = sigm(accr[r] + br_d);
      float zg = sigm(accz[r] + bz_d);
      float ng = tanh_(gin[r] + bin_d + rg*(accn2[r] + bhn_d));
      hreg[r] = ng + zg*(hreg[r] - ng);
    }
    #pragma unroll
    for (int r = 0; r < 4; ++r)
      *(unsigned short*)(hw + (mt*16 + quad*4 + r)*PW + col*2) = f2bf(hreg[r]);
    __syncthreads();   // D1: h(s+1) visible

    // fc1: (32x128)@(128x256)+relu -> a1; wave w owns out-cols w*16..+15, both row halves
    {
      short8 hf[2][4];
      #pragma unroll
      for (int m2 = 0; m2 < 2; ++m2)
        #pragma unroll
        for (int kt = 0; kt < 4; ++kt)
          hf[m2][kt] = *(const short8*)(hw + (m2*16 + l15)*PW + kt*64 + quad*16);
      f32x4 a1a[2];
      a1a[0] = (f32x4){0.f,0.f,0.f,0.f}; a1a[1] = a1a[0];
      #pragma unroll
      for (int kt = 0; kt < 4; ++kt){
        a1a[0] = mfma16(hf[0][kt], f1f[kt], a1a[0]);
        a1a[1] = mfma16(hf[1][kt], f1f[kt], a1a[1]);
      }
      #pragma unroll
      for (int m2 = 0; m2 < 2; ++m2)
        #pragma unroll
        for (int r = 0; r < 4; ++r)
          *(unsigned short*)(smem + O_A1D + (m2*16 + quad*4 + r)*PITCH2 +
                             (w*16 + l15)*2) = f2bf(fmaxf(a1a[m2][r] + fb1, 0.f));
    }
    __syncthreads();   // D2: a1 visible

    // fused fc2+fc3: out6 = a1 @ W32^T + b32; waves 0-1 only, no barrier (reads precede
    // next step's a1 writes, which are gated by D1 that waves 0-1 must also pass).
    if (w < 2){
      f32x4 acc = (f32x4){0.f,0.f,0.f,0.f};
      #pragma unroll
      for (int kt = 0; kt < 8; ++kt){
        short8 a   = *(const short8*)(smem + O_A1D + (w*16 + l15)*PITCH2 + kt*64 + quad*16);
        short8 bfr = *(const short8*)(smem + O_W32 + l15*PITCH2 + kt*64 + quad*16);
        acc = mfma16(a, bfr, acc);
      }
      if (l15 < 6){
        #pragma unroll
        for (int r = 0; r < 4; ++r){
          pres[r] += acc[r] + b32v;
          out[(size_t)(b0 + w*16 + quad*4 + r)*180 + l15*30 + s] = pres[r];   // (B, 6, 30)
        }
      }
    }
  }
}

extern "C" void kernel_launch(void* const* d_in, const int* in_sizes, int n_in,
                              void* d_out, int out_size, void* d_ws, size_t ws_size,
                              hipStream_t stream) {
  (void)in_sizes; (void)n_in; (void)out_size; (void)d_ws; (void)ws_size;
  const float* past     = (const float*)d_in[0];
  const float* conv_w   = (const float*)d_in[1];
  const float* conv_b   = (const float*)d_in[2];
  const float* bn_gamma = (const float*)d_in[3];
  const float* bn_beta  = (const float*)d_in[4];
  const float* bn_mean  = (const float*)d_in[5];
  const float* bn_var   = (const float*)d_in[6];
  const float* enc_wih  = (const float*)d_in[7];
  const float* enc_whh  = (const float*)d_in[8];
  const float* enc_bih  = (const float*)d_in[9];
  const float* enc_bhh  = (const float*)d_in[10];
  const float* dec_wih  = (const float*)d_in[11];
  const float* dec_whh  = (const float*)d_in[12];
  const float* dec_bih  = (const float*)d_in[13];
  const float* dec_bhh  = (const float*)d_in[14];
  const float* fc1_w    = (const float*)d_in[15];
  const float* fc1_b    = (const float*)d_in[16];
  const float* fc2_w    = (const float*)d_in[17];
  const float* fc2_b    = (const float*)d_in[18];
  const float* fc3_w    = (const float*)d_in[19];
  const float* fc3_b    = (const float*)d_in[20];

  hipFuncSetAttribute((const void*)gru_fused,
                      hipFuncAttributeMaxDynamicSharedMemorySize, LDS_TOTAL);

  gru_fused<<<NBLK, THREADS, LDS_TOTAL, stream>>>(
      past, conv_w, conv_b, bn_gamma, bn_beta, bn_mean, bn_var,
      enc_wih, enc_whh, enc_bih, enc_bhh,
      dec_wih, dec_whh, dec_bih, dec_bhh,
      fc1_w, fc1_b, fc2_w, fc2_b, fc3_w, fc3_b,
      (float*)d_out);
}